// Round 10
// baseline (335.805 us; speedup 1.0000x reference)
//
#include <hip/hip_runtime.h>
#include <math.h>

// CILRS fused head — round 17.
//  Base = round 16 (147 µs; spill eliminated, VALUBusy 30% > MfmaUtil 19.5%).
//  New lever: phase-1 B-operand (sh = relu(speed*sw1+sb1)) was recomputed by
//  EVERY wave EVERY pass (16x redundancy, ~half of all VALU). Now: compute sh
//  ONCE into LDS (overlaying s_x — dead before emb staging), phase-1 MFMA
//  reads B via ds_read_b128. Phase 1 un-split (dacc[4][4]; VALU temps gone,
//  no spill expected — WRITE_SIZE is the tripwire). Phases 3/4 = r16 exactly.
//  Keep: 64-row/512-thr/2-blk-CU, XCD swizzle, NT emb loads, setprio, k_count.

#define B_ 65536
#define D_ 512
#define H_ 256

typedef float  f32x4   __attribute__((ext_vector_type(4)));
typedef __bf16 bf16x8  __attribute__((ext_vector_type(8)));
typedef __bf16 bf16x4  __attribute__((ext_vector_type(4)));
typedef float  float4v __attribute__((ext_vector_type(4)));

// ---- ws layout (bytes) ----
// [0..23]  counts[6]   (zeroed by hipMemsetAsync)
// [24..47] cursor2[6]  (zeroed by hipMemsetAsync)
#define OFF_PERM     256        // 65536 ints
#define OFF_PACK     262400     // packed bf16 weights (3,014,656 B)
#define WS_NEEDED    3277056

// packed element offsets (bf16 elements, relative to PK); layout [kc][n][32k]
#define PKO_SW2   0u
#define PKO_BW1   131072u
#define PKO_BW2   917504u
#define PKO_OW1   1310720u
#define PKO_OW2   1441792u

#define PITCH_E 520   // row pitch (bf16) for the 64x512 tile

// ---------------- prep 1: 64-block histogram ----------------

__global__ __launch_bounds__(256) void k_count(const int* __restrict__ command,
                                               int* __restrict__ counts) {
    __shared__ int lh[6];
    int t = threadIdx.x;
    if (t < 6) lh[t] = 0;
    __syncthreads();
    int i = blockIdx.x * 256 + t;
    int4 v = ((const int4*)command)[i];
    int a[4] = {v.x, v.y, v.z, v.w};
    #pragma unroll
    for (int j = 0; j < 4; ++j) {
        int c = min(max(a[j] - 1, 0), 5);
        atomicAdd(&lh[c], 1);
    }
    __syncthreads();
    if (t < 6) atomicAdd(&counts[t], lh[t]);
}

// ---------------- prep 2: scatter + pack fused ----------------

__global__ __launch_bounds__(256) void k_prepB(const int* __restrict__ command,
                                               const int* __restrict__ counts,
                                               int* __restrict__ cursor2,
                                               int* __restrict__ perm,
                                               const float* __restrict__ sw2,
                                               const float* __restrict__ bw1,
                                               const float* __restrict__ bw2,
                                               const float* __restrict__ ow1,
                                               const float* __restrict__ ow2,
                                               __bf16* __restrict__ PK) {
    int t = threadIdx.x;
    if (blockIdx.x < 256) {
        // ---- scatter ----
        __shared__ int lh[6], lbase[6];
        if (t < 6) lh[t] = 0;
        __syncthreads();
        int i = blockIdx.x * 256 + t;
        int c = command[i] - 1; c = min(max(c, 0), 5);
        int rank = atomicAdd(&lh[c], 1);
        __syncthreads();
        if (t < 6) {
            int base = 0;
            #pragma unroll
            for (int k = 0; k < 6; ++k) base += (k < t) ? counts[k] : 0;
            lbase[t] = base + atomicAdd(&cursor2[t], lh[t]);
        }
        __syncthreads();
        perm[lbase[c] + rank] = i;
        return;
    }
    // ---- pack: W [C][K][N] fp32 -> PK bf16 [kc][n][32k] ----
    int b = blockIdx.x - 256;
    const float* src; int srcN, colOff; unsigned dstOff; int tt;
    if (b < 64)       { int s = b >> 5;        tt = b & 31;  src = sw2;                          srcN = 512; colOff = s * 256; dstOff = PKO_SW2 + s * 65536u; }
    else if (b < 448) { int i = b - 64;  int c = i >> 6; tt = i & 63; src = bw1 + (size_t)c * 512 * 256; srcN = 256; colOff = 0; dstOff = PKO_BW1 + c * 131072u; }
    else if (b < 640) { int i = b - 448; int c = i >> 5; tt = i & 31; src = bw2 + (size_t)c * 256 * 256; srcN = 256; colOff = 0; dstOff = PKO_BW2 + c * 65536u; }
    else if (b < 704) { tt = b - 640; src = ow1; srcN = 256; colOff = 0; dstOff = PKO_OW1; }
    else              { tt = b - 704; src = ow2; srcN = 256; colOff = 0; dstOff = PKO_OW2; }
    int kc = tt >> 2, nt = tt & 3;
    int k0 = kc * 32, n0 = nt * 64;

    __shared__ __bf16 T[64][34];
    #pragma unroll
    for (int p = 0; p < 2; ++p) {
        int idx = p * 256 + t;            // 512 chunks: 32 k x 16 n4
        int k = idx >> 4, n4 = idx & 15;
        float4v v = *(const float4v*)(src + (size_t)(k0 + k) * srcN + colOff + n0 + n4 * 4);
        T[n4 * 4 + 0][k] = (__bf16)v[0];
        T[n4 * 4 + 1][k] = (__bf16)v[1];
        T[n4 * 4 + 2][k] = (__bf16)v[2];
        T[n4 * 4 + 3][k] = (__bf16)v[3];
    }
    __syncthreads();
    int n = t >> 2, seg = t & 3;
    bf16x8 v;
    #pragma unroll
    for (int j = 0; j < 8; ++j) v[j] = T[n][seg * 8 + j];
    *(bf16x8*)(PK + dstOff + ((unsigned)(kc * 256 + n0 + n) * 32u + seg * 8u)) = v;
}

// ---------------- fused main: 64 rows/block, 8 waves, single 64x512 LDS buffer ----------------

__global__ __launch_bounds__(512, 4) void k_fused(
    const float* __restrict__ embedding, const float* __restrict__ speed,
    const int*   __restrict__ command,
    const float* __restrict__ sw1, const float* __restrict__ sb1,
    const float* __restrict__ sb2,
    const float* __restrict__ bb1, const float* __restrict__ bb2,
    const float* __restrict__ bw3, const float* __restrict__ bb3,
    const float* __restrict__ ob1, const float* __restrict__ ob2,
    const float* __restrict__ ow3, const float* __restrict__ ob3,
    const int* __restrict__ perm, const __bf16* __restrict__ PK,
    float* __restrict__ out)
{
    __shared__ __bf16 s_x[64 * PITCH_E];     // 66.6 KB: sh, then emb, then [h1|t1]
    __shared__ float  s_head[64][4];
    __shared__ int    s_row[64];
    __shared__ int    s_cmd[64];
    __shared__ float  s_spd[64];

    const int tid = threadIdx.x;
    const int w = tid >> 6, lane = tid & 63;
    const int lm = lane & 15, kg = lane >> 4;
    // XCD-aware swizzle (grid=1024, 8 XCDs, bijective): XCD x gets orig blocks
    // [x*128, (x+1)*128) — contiguous in command-sorted perm -> small L2 set.
    const int obid = ((int)blockIdx.x & 7) * 128 + ((int)blockIdx.x >> 3);
    const int R0 = obid * 64;

    if (tid < 64) {
        int r = perm[R0 + tid];
        s_row[tid] = r;
        int c = command[r] - 1; c = min(max(c, 0), 5);
        s_cmd[tid] = c;
        s_spd[tid] = speed[r];
        s_head[tid][0] = 0.f; s_head[tid][1] = 0.f; s_head[tid][2] = 0.f; s_head[tid][3] = 0.f;
    }
    __syncthreads();

    // ---- phase 0: sh = relu(speed*sw1+sb1) computed ONCE -> LDS (cols 0-255) ----
    {
        int row = tid >> 3, h0 = (tid & 7) * 32;
        float spd = s_spd[row];
        #pragma unroll
        for (int j = 0; j < 32; j += 4) {
            float4v wv = *(const float4v*)(sw1 + h0 + j);
            float4v cv = *(const float4v*)(sb1 + h0 + j);
            bf16x4 pv;
            #pragma unroll
            for (int g = 0; g < 4; ++g)
                pv[g] = (__bf16)fmaxf(spd * wv[g] + cv[g], 0.f);
            *(bf16x4*)(s_x + row * PITCH_E + h0 + j) = pv;
        }
    }
    __syncthreads();

    // ---- phase 1 MFMA: deltaT = sw2T @ shT; A from PK, B from LDS ----
    const unsigned slice = (unsigned)(w >> 2) * 65536u;
    const int mbase = (w & 3) * 64;
    f32x4 dacc[4][4];
    {
        const __bf16* shb = s_x + lm * PITCH_E + kg * 8;
        #pragma unroll
        for (int mt = 0; mt < 4; ++mt)
            #pragma unroll
            for (int nt = 0; nt < 4; ++nt) dacc[mt][nt] = f32x4{0.f, 0.f, 0.f, 0.f};
        #pragma unroll 4
        for (int ks = 0; ks < 8; ++ks) {
            bf16x8 bns[4];
            #pragma unroll
            for (int nt = 0; nt < 4; ++nt)
                bns[nt] = *(const bf16x8*)(shb + nt * 16 * PITCH_E + ks * 32);
            const __bf16* ap = PK + PKO_SW2 + slice + (size_t)ks * 8192
                             + (size_t)(mbase + lm) * 32 + kg * 8;
            __builtin_amdgcn_s_setprio(1);
            #pragma unroll
            for (int mt = 0; mt < 4; ++mt) {
                bf16x8 av = *(const bf16x8*)(ap + mt * 512);
                #pragma unroll
                for (int nt = 0; nt < 4; ++nt)
                    dacc[mt][nt] = __builtin_amdgcn_mfma_f32_16x16x32_bf16(av, bns[nt], dacc[mt][nt], 0, 0, 0);
            }
            __builtin_amdgcn_s_setprio(0);
        }
    }
    __syncthreads();   // sh dead; safe to overwrite s_x

    // ---- stage embedding -> LDS bf16 (NT: evict-first, protect PK in L2) ----
    #pragma unroll
    for (int it = 0; it < 16; ++it) {
        int idx = it * 512 + tid;          // 8192 chunks: 64 rows x 128
        int row = idx >> 7, c4 = idx & 127;
        float4v v = __builtin_nontemporal_load(
            (const float4v*)(embedding + (size_t)s_row[row] * D_ + c4 * 4));
        bf16x4 pv;
        pv[0] = (__bf16)v[0]; pv[1] = (__bf16)v[1];
        pv[2] = (__bf16)v[2]; pv[3] = (__bf16)v[3];
        *(bf16x4*)(s_x + row * PITCH_E + c4 * 4) = pv;
    }
    __syncthreads();

    const int cmin = s_cmd[0], cmax = s_cmd[63];   // perm is bucket-sorted

    // ---- phase 1 RMW epilogue: s_x += deltaT + sb2 ----
    {
        #pragma unroll
        for (int mt = 0; mt < 4; ++mt) {
            int colb = w * 64 + mt * 16 + kg * 4;
            float4v sbv = *(const float4v*)(sb2 + colb);
            #pragma unroll
            for (int nt = 0; nt < 4; ++nt) {
                int row = nt * 16 + lm;
                bf16x4* p = (bf16x4*)(s_x + row * PITCH_E + colb);
                bf16x4 old = *p;
                bf16x4 nv;
                #pragma unroll
                for (int g = 0; g < 4; ++g)
                    nv[g] = (__bf16)(dacc[mt][nt][g] + sbv[g] + (float)old[g]);
                *p = nv;
            }
        }
    }
    __syncthreads();

    const bool roleB = (w < 4);
    const int colbase = (w & 3) * 64;
    const unsigned laneoffB = (unsigned)(colbase + lm) * 32u + kg * 8u;
    const __bf16* aXbase = s_x + lm * PITCH_E + kg * 8;   // + mt*16*PITCH_E

    // ---- phase 3: h1 (waves 0-3, c-loop) | t1 (waves 4-7); ct-split (32 AGPR) ----
    bf16x4 res[4][4];   // [mt][ct]
    if (roleB) {
        for (int c = cmin; c <= cmax; ++c) {
            const __bf16* bb = PK + PKO_BW1 + (unsigned)c * 131072u + laneoffB;
            #pragma unroll
            for (int ch = 0; ch < 2; ++ch) {
                f32x4 ah[4][2];
                #pragma unroll
                for (int mt = 0; mt < 4; ++mt) {
                    ah[mt][0] = f32x4{0.f, 0.f, 0.f, 0.f};
                    ah[mt][1] = f32x4{0.f, 0.f, 0.f, 0.f};
                }
                #pragma unroll 4
                for (int ks = 0; ks < 16; ++ks) {
                    bf16x8 a[4];
                    #pragma unroll
                    for (int mt = 0; mt < 4; ++mt)
                        a[mt] = *(const bf16x8*)(aXbase + mt * 16 * PITCH_E + ks * 32);
                    __builtin_amdgcn_s_setprio(1);
                    #pragma unroll
                    for (int ct2 = 0; ct2 < 2; ++ct2) {
                        bf16x8 bv = *(const bf16x8*)(bb + (size_t)ks * 8192 + (ch * 2 + ct2) * 512);
                        #pragma unroll
                        for (int mt = 0; mt < 4; ++mt)
                            ah[mt][ct2] = __builtin_amdgcn_mfma_f32_16x16x32_bf16(a[mt], bv, ah[mt][ct2], 0, 0, 0);
                    }
                    __builtin_amdgcn_s_setprio(0);
                }
                #pragma unroll
                for (int ct2 = 0; ct2 < 2; ++ct2) {
                    int ct = ch * 2 + ct2;
                    int col = colbase + ct * 16 + lm;
                    float b = bb1[c * H_ + col];
                    #pragma unroll
                    for (int mt = 0; mt < 4; ++mt)
                        #pragma unroll
                        for (int g = 0; g < 4; ++g)
                            if (s_cmd[mt * 16 + kg * 4 + g] == c)
                                res[mt][ct][g] = (__bf16)fmaxf(ah[mt][ct2][g] + b, 0.f);
                }
            }
        }
    } else {
        const __bf16* bb = PK + PKO_OW1 + laneoffB;
        #pragma unroll
        for (int ch = 0; ch < 2; ++ch) {
            f32x4 ta[4][2];
            #pragma unroll
            for (int mt = 0; mt < 4; ++mt) {
                ta[mt][0] = f32x4{0.f, 0.f, 0.f, 0.f};
                ta[mt][1] = f32x4{0.f, 0.f, 0.f, 0.f};
            }
            #pragma unroll 4
            for (int ks = 0; ks < 16; ++ks) {
                bf16x8 a[4];
                #pragma unroll
                for (int mt = 0; mt < 4; ++mt)
                    a[mt] = *(const bf16x8*)(aXbase + mt * 16 * PITCH_E + ks * 32);
                __builtin_amdgcn_s_setprio(1);
                #pragma unroll
                for (int ct2 = 0; ct2 < 2; ++ct2) {
                    bf16x8 bv = *(const bf16x8*)(bb + (size_t)ks * 8192 + (ch * 2 + ct2) * 512);
                    #pragma unroll
                    for (int mt = 0; mt < 4; ++mt)
                        ta[mt][ct2] = __builtin_amdgcn_mfma_f32_16x16x32_bf16(a[mt], bv, ta[mt][ct2], 0, 0, 0);
                }
                __builtin_amdgcn_s_setprio(0);
            }
            #pragma unroll
            for (int ct2 = 0; ct2 < 2; ++ct2) {
                int ct = ch * 2 + ct2;
                int col = colbase + ct * 16 + lm;
                float b = ob1[col];
                #pragma unroll
                for (int mt = 0; mt < 4; ++mt)
                    #pragma unroll
                    for (int g = 0; g < 4; ++g)
                        res[mt][ct][g] = (__bf16)fmaxf(ta[mt][ct2][g] + b, 0.f);
            }
        }
    }
    __syncthreads();   // all emb reads complete before overwrite

    // ---- write [h1 | t1] back into s_x ----
    {
        const int colW = (roleB ? 0 : 256) + colbase;
        #pragma unroll
        for (int ct = 0; ct < 4; ++ct) {
            int col = colW + ct * 16 + lm;
            #pragma unroll
            for (int mt = 0; mt < 4; ++mt)
                #pragma unroll
                for (int g = 0; g < 4; ++g)
                    s_x[(mt * 16 + kg * 4 + g) * PITCH_E + col] = res[mt][ct][g];
        }
    }
    __syncthreads();

    // ---- phase 4: h2+control (waves 0-3) | t2+speed (waves 4-7), two row-halves ----
    const __bf16* aHbase = s_x + lm * PITCH_E + (roleB ? 0 : 256) + kg * 8;
    if (roleB) {
        for (int c = cmin; c <= cmax; ++c) {
            const __bf16* bb = PK + PKO_BW2 + (unsigned)c * 65536u + laneoffB;
            #pragma unroll
            for (int rh = 0; rh < 2; ++rh) {
                f32x4 hh[2][4];
                #pragma unroll
                for (int mt = 0; mt < 2; ++mt)
                    #pragma unroll
                    for (int ct = 0; ct < 4; ++ct) hh[mt][ct] = f32x4{0.f, 0.f, 0.f, 0.f};
                #pragma unroll 4
                for (int ks = 0; ks < 8; ++ks) {
                    bf16x8 a0 = *(const bf16x8*)(aHbase + (rh * 2 + 0) * 16 * PITCH_E + ks * 32);
                    bf16x8 a1 = *(const bf16x8*)(aHbase + (rh * 2 + 1) * 16 * PITCH_E + ks * 32);
                    __builtin_amdgcn_s_setprio(1);
                    #pragma unroll
                    for (int ct = 0; ct < 4; ++ct) {
                        bf16x8 bv = *(const bf16x8*)(bb + (size_t)ks * 8192 + ct * 512);
                        hh[0][ct] = __builtin_amdgcn_mfma_f32_16x16x32_bf16(a0, bv, hh[0][ct], 0, 0, 0);
                        hh[1][ct] = __builtin_amdgcn_mfma_f32_16x16x32_bf16(a1, bv, hh[1][ct], 0, 0, 0);
                    }
                    __builtin_amdgcn_s_setprio(0);
                }
                float ph[2][4][3];
                #pragma unroll
                for (int mt = 0; mt < 2; ++mt)
                    #pragma unroll
                    for (int g = 0; g < 4; ++g) { ph[mt][g][0] = 0.f; ph[mt][g][1] = 0.f; ph[mt][g][2] = 0.f; }
                #pragma unroll
                for (int ct = 0; ct < 4; ++ct) {
                    int col = colbase + ct * 16 + lm;
                    float b  = bb2[c * H_ + col];
                    float w0 = bw3[(c * H_ + col) * 3 + 0];
                    float w1 = bw3[(c * H_ + col) * 3 + 1];
                    float w2 = bw3[(c * H_ + col) * 3 + 2];
                    #pragma unroll
                    for (int mt = 0; mt < 2; ++mt)
                        #pragma unroll
                        for (int g = 0; g < 4; ++g) {
                            float h = fmaxf(hh[mt][ct][g] + b, 0.f);
                            ph[mt][g][0] += h * w0; ph[mt][g][1] += h * w1; ph[mt][g][2] += h * w2;
                        }
                }
                #pragma unroll
                for (int mt = 0; mt < 2; ++mt)
                    #pragma unroll
                    for (int g = 0; g < 4; ++g)
                        #pragma unroll
                        for (int o = 0; o < 3; ++o) {
                            float v = ph[mt][g][o];
                            v += __shfl_xor(v, 1); v += __shfl_xor(v, 2);
                            v += __shfl_xor(v, 4); v += __shfl_xor(v, 8);
                            ph[mt][g][o] = v;
                        }
                if (lm == 0) {
                    #pragma unroll
                    for (int mt = 0; mt < 2; ++mt)
                        #pragma unroll
                        for (int g = 0; g < 4; ++g) {
                            int row = (rh * 2 + mt) * 16 + kg * 4 + g;
                            if (s_cmd[row] == c) {
                                atomicAdd(&s_head[row][0], ph[mt][g][0]);
                                atomicAdd(&s_head[row][1], ph[mt][g][1]);
                                atomicAdd(&s_head[row][2], ph[mt][g][2]);
                            }
                        }
                }
            }
        }
    } else {
        float sp[4][4];
        #pragma unroll
        for (int mt = 0; mt < 4; ++mt)
            #pragma unroll
            for (int g = 0; g < 4; ++g) sp[mt][g] = 0.f;
        const __bf16* bb = PK + PKO_OW2 + laneoffB;
        #pragma unroll
        for (int rh = 0; rh < 2; ++rh) {
            f32x4 hh[2][4];
            #pragma unroll
            for (int mt = 0; mt < 2; ++mt)
                #pragma unroll
                for (int ct = 0; ct < 4; ++ct) hh[mt][ct] = f32x4{0.f, 0.f, 0.f, 0.f};
            #pragma unroll 4
            for (int ks = 0; ks < 8; ++ks) {
                bf16x8 a0 = *(const bf16x8*)(aHbase + (rh * 2 + 0) * 16 * PITCH_E + ks * 32);
                bf16x8 a1 = *(const bf16x8*)(aHbase + (rh * 2 + 1) * 16 * PITCH_E + ks * 32);
                __builtin_amdgcn_s_setprio(1);
                #pragma unroll
                for (int ct = 0; ct < 4; ++ct) {
                    bf16x8 bv = *(const bf16x8*)(bb + (size_t)ks * 8192 + ct * 512);
                    hh[0][ct] = __builtin_amdgcn_mfma_f32_16x16x32_bf16(a0, bv, hh[0][ct], 0, 0, 0);
                    hh[1][ct] = __builtin_amdgcn_mfma_f32_16x16x32_bf16(a1, bv, hh[1][ct], 0, 0, 0);
                }
                __builtin_amdgcn_s_setprio(0);
            }
            #pragma unroll
            for (int ct = 0; ct < 4; ++ct) {
                int col = colbase + ct * 16 + lm;
                float b = ob2[col], wv = ow3[col];
                #pragma unroll
                for (int mt = 0; mt < 2; ++mt)
                    #pragma unroll
                    for (int g = 0; g < 4; ++g)
                        sp[rh * 2 + mt][g] += fmaxf(hh[mt][ct][g] + b, 0.f) * wv;
            }
        }
        #pragma unroll
        for (int mt = 0; mt < 4; ++mt)
            #pragma unroll
            for (int g = 0; g < 4; ++g) {
                float v = sp[mt][g];
                v += __shfl_xor(v, 1); v += __shfl_xor(v, 2);
                v += __shfl_xor(v, 4); v += __shfl_xor(v, 8);
                if (lm == 0) atomicAdd(&s_head[mt * 16 + kg * 4 + g][3], v);
            }
    }
    __syncthreads();

    if (tid < 64) {
        int r = s_row[tid], c = s_cmd[tid];
        #pragma unroll
        for (int o = 0; o < 3; ++o) {
            float x = s_head[tid][o] + bb3[c * 3 + o];
            __builtin_nontemporal_store(1.f / (1.f + __expf(-x)), &out[(size_t)r * 3 + o]);
        }
        __builtin_nontemporal_store(s_head[tid][3] + ob3[0], &out[(size_t)3 * B_ + r]);
    }
}

// ---------------- fallback (fp32, no ws) ----------------

__global__ __launch_bounds__(256) void cilrs_slow(
    const float* __restrict__ embedding, const float* __restrict__ speed,
    const int* __restrict__ command,
    const float* __restrict__ sw1, const float* __restrict__ sb1,
    const float* __restrict__ sw2, const float* __restrict__ sb2,
    const float* __restrict__ bw1, const float* __restrict__ bb1,
    const float* __restrict__ bw2, const float* __restrict__ bb2,
    const float* __restrict__ bw3, const float* __restrict__ bb3,
    const float* __restrict__ ow1, const float* __restrict__ ob1,
    const float* __restrict__ ow2, const float* __restrict__ ob2,
    const float* __restrict__ ow3, const float* __restrict__ ob3,
    float* __restrict__ out)
{
    const int row = blockIdx.x;
    const int j   = threadIdx.x;
    __shared__ float sh[H_];
    __shared__ float emb[D_];
    __shared__ float h1[H_];
    __shared__ float h2[H_];
    const float spd = speed[row];
    { float v = spd * sw1[j] + sb1[j]; sh[j] = v > 0.f ? v : 0.f; }
    __syncthreads();
    {
        float a0 = 0.f, a1 = 0.f;
        for (int h = 0; h < H_; ++h) {
            const float s = sh[h];
            a0 += s * sw2[h * D_ + j];
            a1 += s * sw2[h * D_ + j + 256];
        }
        emb[j]       = embedding[(size_t)row * D_ + j]       + a0 + sb2[j];
        emb[j + 256] = embedding[(size_t)row * D_ + j + 256] + a1 + sb2[j + 256];
    }
    __syncthreads();
    const int n = command[row] - 1;
    {
        const float* wp = bw1 + (size_t)n * D_ * H_;
        float a = 0.f;
        for (int d = 0; d < D_; ++d) a += emb[d] * wp[d * H_ + j];
        a += bb1[n * H_ + j];
        h1[j] = a > 0.f ? a : 0.f;
    }
    __syncthreads();
    {
        const float* wp = bw2 + (size_t)n * H_ * H_;
        float a = 0.f;
        for (int h = 0; h < H_; ++h) a += h1[h] * wp[h * H_ + j];
        a += bb2[n * H_ + j];
        h2[j] = a > 0.f ? a : 0.f;
    }
    __syncthreads();
    {
        float a = 0.f;
        for (int d = 0; d < D_; ++d) a += emb[d] * ow1[d * H_ + j];
        a += ob1[j];
        sh[j] = a > 0.f ? a : 0.f;
    }
    __syncthreads();
    {
        float a = 0.f;
        for (int h = 0; h < H_; ++h) a += sh[h] * ow2[h * H_ + j];
        a += ob2[j];
        h1[j] = a > 0.f ? a : 0.f;
    }
    __syncthreads();
    if (j < 3) {
        const float* wp = bw3 + (size_t)n * H_ * 3;
        float a = 0.f;
        for (int h = 0; h < H_; ++h) a += h2[h] * wp[h * 3 + j];
        a += bb3[n * 3 + j];
        out[(size_t)row * 3 + j] = 1.f / (1.f + expf(-a));
    } else if (j == 3) {
        float a = 0.f;
        for (int h = 0; h < H_; ++h) a += h1[h] * ow3[h];
        a += ob3[0];
        out[(size_t)B_ * 3 + row] = a;
    }
}

// ---------------- launch ----------------

extern "C" void kernel_launch(void* const* d_in, const int* in_sizes, int n_in,
                              void* d_out, int out_size, void* d_ws, size_t ws_size,
                              hipStream_t stream) {
    const float* embedding = (const float*)d_in[0];
    const float* speed     = (const float*)d_in[1];
    const int*   command   = (const int*)  d_in[2];
    const float* sw1 = (const float*)d_in[3];
    const float* sb1 = (const float*)d_in[4];
    const float* sw2 = (const float*)d_in[5];
    const float* sb2 = (const float*)d_in[6];
    const float* bw1 = (const float*)d_in[7];
    const float* bb1 = (const float*)d_in[8];
    const float* bw2 = (const float*)d_in[9];
    const float* bb2 = (const float*)d_in[10];
    const float* bw3 = (const float*)d_in[11];
    const float* bb3 = (const float*)d_in[12];
    const float* ow1 = (const float*)d_in[13];
    const float* ob1 = (const float*)d_in[14];
    const float* ow2 = (const float*)d_in[15];
    const float* ob2 = (const float*)d_in[16];
    const float* ow3 = (const float*)d_in[17];
    const float* ob3 = (const float*)d_in[18];
    float* out = (float*)d_out;

    if (ws_size < (size_t)WS_NEEDED) {
        cilrs_slow<<<B_, 256, 0, stream>>>(embedding, speed, command,
                                           sw1, sb1, sw2, sb2,
                                           bw1, bb1, bw2, bb2, bw3, bb3,
                                           ow1, ob1, ow2, ob2, ow3, ob3, out);
        return;
    }

    char* ws = (char*)d_ws;
    int*    counts  = (int*)    ws;          // [0..23]
    int*    cursor2 = (int*)   (ws + 24);    // [24..47]
    int*    perm    = (int*)   (ws + OFF_PERM);
    __bf16* PK      = (__bf16*)(ws + OFF_PACK);

    hipMemsetAsync(ws, 0, 64, stream);
    k_count<<<64, 256, 0, stream>>>(command, counts);
    k_prepB<<<992, 256, 0, stream>>>(command, counts, cursor2, perm,
                                     sw2, bw1, bw2, ow1, ow2, PK);
    k_fused<<<B_ / 64, 512, 0, stream>>>(embedding, speed, command,
                                         sw1, sb1, sb2,
                                         bb1, bb2, bw3, bb3,
                                         ob1, ob2, ow3, ob3,
                                         perm, PK, out);
}

// Round 11
// 335.230 us; speedup vs baseline: 1.0017x; 1.0017x over previous
//
#include <hip/hip_runtime.h>
#include <math.h>

// CILRS fused head — round 18.
//  Base = round 17 (146 µs). r17 diagnosis: dacc[4][4] (64 AGPR) stayed live
//  across the staging loop -> staging's in-flight loads overflowed the 128-reg
//  cap (WRITE_SIZE 3.3->7.1 MB spill). Fix: write deltaT+sb2 into s_x as bf16
//  right after phase-1 (dacc dies), then staging itself does the RMW
//  (s_x = bf16(old + emb)). Frees all regs for staging pipelining, merges the
//  RMW epilogue into staging, keeps phase-1 un-split + sh-from-LDS (low VALU).
//  Keep: 64-row/512-thr/2-blk-CU, XCD swizzle, NT emb loads, setprio, k_count.

#define B_ 65536
#define D_ 512
#define H_ 256

typedef float  f32x4   __attribute__((ext_vector_type(4)));
typedef __bf16 bf16x8  __attribute__((ext_vector_type(8)));
typedef __bf16 bf16x4  __attribute__((ext_vector_type(4)));
typedef float  float4v __attribute__((ext_vector_type(4)));

// ---- ws layout (bytes) ----
// [0..23]  counts[6]   (zeroed by hipMemsetAsync)
// [24..47] cursor2[6]  (zeroed by hipMemsetAsync)
#define OFF_PERM     256        // 65536 ints
#define OFF_PACK     262400     // packed bf16 weights (3,014,656 B)
#define WS_NEEDED    3277056

// packed element offsets (bf16 elements, relative to PK); layout [kc][n][32k]
#define PKO_SW2   0u
#define PKO_BW1   131072u
#define PKO_BW2   917504u
#define PKO_OW1   1310720u
#define PKO_OW2   1441792u

#define PITCH_E 520   // row pitch (bf16) for the 64x512 tile

// ---------------- prep 1: 64-block histogram ----------------

__global__ __launch_bounds__(256) void k_count(const int* __restrict__ command,
                                               int* __restrict__ counts) {
    __shared__ int lh[6];
    int t = threadIdx.x;
    if (t < 6) lh[t] = 0;
    __syncthreads();
    int i = blockIdx.x * 256 + t;
    int4 v = ((const int4*)command)[i];
    int a[4] = {v.x, v.y, v.z, v.w};
    #pragma unroll
    for (int j = 0; j < 4; ++j) {
        int c = min(max(a[j] - 1, 0), 5);
        atomicAdd(&lh[c], 1);
    }
    __syncthreads();
    if (t < 6) atomicAdd(&counts[t], lh[t]);
}

// ---------------- prep 2: scatter + pack fused ----------------

__global__ __launch_bounds__(256) void k_prepB(const int* __restrict__ command,
                                               const int* __restrict__ counts,
                                               int* __restrict__ cursor2,
                                               int* __restrict__ perm,
                                               const float* __restrict__ sw2,
                                               const float* __restrict__ bw1,
                                               const float* __restrict__ bw2,
                                               const float* __restrict__ ow1,
                                               const float* __restrict__ ow2,
                                               __bf16* __restrict__ PK) {
    int t = threadIdx.x;
    if (blockIdx.x < 256) {
        // ---- scatter ----
        __shared__ int lh[6], lbase[6];
        if (t < 6) lh[t] = 0;
        __syncthreads();
        int i = blockIdx.x * 256 + t;
        int c = command[i] - 1; c = min(max(c, 0), 5);
        int rank = atomicAdd(&lh[c], 1);
        __syncthreads();
        if (t < 6) {
            int base = 0;
            #pragma unroll
            for (int k = 0; k < 6; ++k) base += (k < t) ? counts[k] : 0;
            lbase[t] = base + atomicAdd(&cursor2[t], lh[t]);
        }
        __syncthreads();
        perm[lbase[c] + rank] = i;
        return;
    }
    // ---- pack: W [C][K][N] fp32 -> PK bf16 [kc][n][32k] ----
    int b = blockIdx.x - 256;
    const float* src; int srcN, colOff; unsigned dstOff; int tt;
    if (b < 64)       { int s = b >> 5;        tt = b & 31;  src = sw2;                          srcN = 512; colOff = s * 256; dstOff = PKO_SW2 + s * 65536u; }
    else if (b < 448) { int i = b - 64;  int c = i >> 6; tt = i & 63; src = bw1 + (size_t)c * 512 * 256; srcN = 256; colOff = 0; dstOff = PKO_BW1 + c * 131072u; }
    else if (b < 640) { int i = b - 448; int c = i >> 5; tt = i & 31; src = bw2 + (size_t)c * 256 * 256; srcN = 256; colOff = 0; dstOff = PKO_BW2 + c * 65536u; }
    else if (b < 704) { tt = b - 640; src = ow1; srcN = 256; colOff = 0; dstOff = PKO_OW1; }
    else              { tt = b - 704; src = ow2; srcN = 256; colOff = 0; dstOff = PKO_OW2; }
    int kc = tt >> 2, nt = tt & 3;
    int k0 = kc * 32, n0 = nt * 64;

    __shared__ __bf16 T[64][34];
    #pragma unroll
    for (int p = 0; p < 2; ++p) {
        int idx = p * 256 + t;            // 512 chunks: 32 k x 16 n4
        int k = idx >> 4, n4 = idx & 15;
        float4v v = *(const float4v*)(src + (size_t)(k0 + k) * srcN + colOff + n0 + n4 * 4);
        T[n4 * 4 + 0][k] = (__bf16)v[0];
        T[n4 * 4 + 1][k] = (__bf16)v[1];
        T[n4 * 4 + 2][k] = (__bf16)v[2];
        T[n4 * 4 + 3][k] = (__bf16)v[3];
    }
    __syncthreads();
    int n = t >> 2, seg = t & 3;
    bf16x8 v;
    #pragma unroll
    for (int j = 0; j < 8; ++j) v[j] = T[n][seg * 8 + j];
    *(bf16x8*)(PK + dstOff + ((unsigned)(kc * 256 + n0 + n) * 32u + seg * 8u)) = v;
}

// ---------------- fused main: 64 rows/block, 8 waves, single 64x512 LDS buffer ----------------

__global__ __launch_bounds__(512, 4) void k_fused(
    const float* __restrict__ embedding, const float* __restrict__ speed,
    const int*   __restrict__ command,
    const float* __restrict__ sw1, const float* __restrict__ sb1,
    const float* __restrict__ sb2,
    const float* __restrict__ bb1, const float* __restrict__ bb2,
    const float* __restrict__ bw3, const float* __restrict__ bb3,
    const float* __restrict__ ob1, const float* __restrict__ ob2,
    const float* __restrict__ ow3, const float* __restrict__ ob3,
    const int* __restrict__ perm, const __bf16* __restrict__ PK,
    float* __restrict__ out)
{
    __shared__ __bf16 s_x[64 * PITCH_E];     // 66.6 KB: sh, then deltaT, then x, then [h1|t1]
    __shared__ float  s_head[64][4];
    __shared__ int    s_row[64];
    __shared__ int    s_cmd[64];
    __shared__ float  s_spd[64];

    const int tid = threadIdx.x;
    const int w = tid >> 6, lane = tid & 63;
    const int lm = lane & 15, kg = lane >> 4;
    // XCD-aware swizzle (grid=1024, 8 XCDs, bijective): XCD x gets orig blocks
    // [x*128, (x+1)*128) — contiguous in command-sorted perm -> small L2 set.
    const int obid = ((int)blockIdx.x & 7) * 128 + ((int)blockIdx.x >> 3);
    const int R0 = obid * 64;

    if (tid < 64) {
        int r = perm[R0 + tid];
        s_row[tid] = r;
        int c = command[r] - 1; c = min(max(c, 0), 5);
        s_cmd[tid] = c;
        s_spd[tid] = speed[r];
        s_head[tid][0] = 0.f; s_head[tid][1] = 0.f; s_head[tid][2] = 0.f; s_head[tid][3] = 0.f;
    }
    __syncthreads();

    // ---- phase 0: sh = relu(speed*sw1+sb1) computed ONCE -> LDS (cols 0-255) ----
    {
        int row = tid >> 3, h0 = (tid & 7) * 32;
        float spd = s_spd[row];
        #pragma unroll
        for (int j = 0; j < 32; j += 4) {
            float4v wv = *(const float4v*)(sw1 + h0 + j);
            float4v cv = *(const float4v*)(sb1 + h0 + j);
            bf16x4 pv;
            #pragma unroll
            for (int g = 0; g < 4; ++g)
                pv[g] = (__bf16)fmaxf(spd * wv[g] + cv[g], 0.f);
            *(bf16x4*)(s_x + row * PITCH_E + h0 + j) = pv;
        }
    }
    __syncthreads();

    // ---- phase 1 MFMA: deltaT = sw2T @ shT; A from PK, B from LDS ----
    const unsigned slice = (unsigned)(w >> 2) * 65536u;
    const int mbase = (w & 3) * 64;
    {
        f32x4 dacc[4][4];
        const __bf16* shb = s_x + lm * PITCH_E + kg * 8;
        #pragma unroll
        for (int mt = 0; mt < 4; ++mt)
            #pragma unroll
            for (int nt = 0; nt < 4; ++nt) dacc[mt][nt] = f32x4{0.f, 0.f, 0.f, 0.f};
        #pragma unroll 4
        for (int ks = 0; ks < 8; ++ks) {
            bf16x8 bns[4];
            #pragma unroll
            for (int nt = 0; nt < 4; ++nt)
                bns[nt] = *(const bf16x8*)(shb + nt * 16 * PITCH_E + ks * 32);
            const __bf16* ap = PK + PKO_SW2 + slice + (size_t)ks * 8192
                             + (size_t)(mbase + lm) * 32 + kg * 8;
            __builtin_amdgcn_s_setprio(1);
            #pragma unroll
            for (int mt = 0; mt < 4; ++mt) {
                bf16x8 av = *(const bf16x8*)(ap + mt * 512);
                #pragma unroll
                for (int nt = 0; nt < 4; ++nt)
                    dacc[mt][nt] = __builtin_amdgcn_mfma_f32_16x16x32_bf16(av, bns[nt], dacc[mt][nt], 0, 0, 0);
            }
            __builtin_amdgcn_s_setprio(0);
        }
        __syncthreads();   // all waves done reading sh

        // ---- write deltaT + sb2 into s_x as bf16; dacc dies here ----
        #pragma unroll
        for (int mt = 0; mt < 4; ++mt) {
            int colb = w * 64 + mt * 16 + kg * 4;
            float4v sbv = *(const float4v*)(sb2 + colb);
            #pragma unroll
            for (int nt = 0; nt < 4; ++nt) {
                int row = nt * 16 + lm;
                bf16x4 nv;
                #pragma unroll
                for (int g = 0; g < 4; ++g)
                    nv[g] = (__bf16)(dacc[mt][nt][g] + sbv[g]);
                *(bf16x4*)(s_x + row * PITCH_E + colb) = nv;
            }
        }
    }
    __syncthreads();

    // ---- stage embedding with fused RMW: s_x = bf16(deltaT + emb) ----
    // No accumulators live -> full register file available for load pipelining.
    #pragma unroll
    for (int it = 0; it < 16; ++it) {
        int idx = it * 512 + tid;          // 8192 chunks: 64 rows x 128
        int row = idx >> 7, c4 = idx & 127;
        float4v v = __builtin_nontemporal_load(
            (const float4v*)(embedding + (size_t)s_row[row] * D_ + c4 * 4));
        bf16x4* p = (bf16x4*)(s_x + row * PITCH_E + c4 * 4);
        bf16x4 old = *p;
        bf16x4 pv;
        pv[0] = (__bf16)((float)old[0] + v[0]);
        pv[1] = (__bf16)((float)old[1] + v[1]);
        pv[2] = (__bf16)((float)old[2] + v[2]);
        pv[3] = (__bf16)((float)old[3] + v[3]);
        *p = pv;
    }
    __syncthreads();

    const int cmin = s_cmd[0], cmax = s_cmd[63];   // perm is bucket-sorted

    const bool roleB = (w < 4);
    const int colbase = (w & 3) * 64;
    const unsigned laneoffB = (unsigned)(colbase + lm) * 32u + kg * 8u;
    const __bf16* aXbase = s_x + lm * PITCH_E + kg * 8;   // + mt*16*PITCH_E

    // ---- phase 3: h1 (waves 0-3, c-loop) | t1 (waves 4-7); ct-split (32 AGPR) ----
    bf16x4 res[4][4];   // [mt][ct]
    if (roleB) {
        for (int c = cmin; c <= cmax; ++c) {
            const __bf16* bb = PK + PKO_BW1 + (unsigned)c * 131072u + laneoffB;
            #pragma unroll
            for (int ch = 0; ch < 2; ++ch) {
                f32x4 ah[4][2];
                #pragma unroll
                for (int mt = 0; mt < 4; ++mt) {
                    ah[mt][0] = f32x4{0.f, 0.f, 0.f, 0.f};
                    ah[mt][1] = f32x4{0.f, 0.f, 0.f, 0.f};
                }
                #pragma unroll 4
                for (int ks = 0; ks < 16; ++ks) {
                    bf16x8 a[4];
                    #pragma unroll
                    for (int mt = 0; mt < 4; ++mt)
                        a[mt] = *(const bf16x8*)(aXbase + mt * 16 * PITCH_E + ks * 32);
                    __builtin_amdgcn_s_setprio(1);
                    #pragma unroll
                    for (int ct2 = 0; ct2 < 2; ++ct2) {
                        bf16x8 bv = *(const bf16x8*)(bb + (size_t)ks * 8192 + (ch * 2 + ct2) * 512);
                        #pragma unroll
                        for (int mt = 0; mt < 4; ++mt)
                            ah[mt][ct2] = __builtin_amdgcn_mfma_f32_16x16x32_bf16(a[mt], bv, ah[mt][ct2], 0, 0, 0);
                    }
                    __builtin_amdgcn_s_setprio(0);
                }
                #pragma unroll
                for (int ct2 = 0; ct2 < 2; ++ct2) {
                    int ct = ch * 2 + ct2;
                    int col = colbase + ct * 16 + lm;
                    float b = bb1[c * H_ + col];
                    #pragma unroll
                    for (int mt = 0; mt < 4; ++mt)
                        #pragma unroll
                        for (int g = 0; g < 4; ++g)
                            if (s_cmd[mt * 16 + kg * 4 + g] == c)
                                res[mt][ct][g] = (__bf16)fmaxf(ah[mt][ct2][g] + b, 0.f);
                }
            }
        }
    } else {
        const __bf16* bb = PK + PKO_OW1 + laneoffB;
        #pragma unroll
        for (int ch = 0; ch < 2; ++ch) {
            f32x4 ta[4][2];
            #pragma unroll
            for (int mt = 0; mt < 4; ++mt) {
                ta[mt][0] = f32x4{0.f, 0.f, 0.f, 0.f};
                ta[mt][1] = f32x4{0.f, 0.f, 0.f, 0.f};
            }
            #pragma unroll 4
            for (int ks = 0; ks < 16; ++ks) {
                bf16x8 a[4];
                #pragma unroll
                for (int mt = 0; mt < 4; ++mt)
                    a[mt] = *(const bf16x8*)(aXbase + mt * 16 * PITCH_E + ks * 32);
                __builtin_amdgcn_s_setprio(1);
                #pragma unroll
                for (int ct2 = 0; ct2 < 2; ++ct2) {
                    bf16x8 bv = *(const bf16x8*)(bb + (size_t)ks * 8192 + (ch * 2 + ct2) * 512);
                    #pragma unroll
                    for (int mt = 0; mt < 4; ++mt)
                        ta[mt][ct2] = __builtin_amdgcn_mfma_f32_16x16x32_bf16(a[mt], bv, ta[mt][ct2], 0, 0, 0);
                }
                __builtin_amdgcn_s_setprio(0);
            }
            #pragma unroll
            for (int ct2 = 0; ct2 < 2; ++ct2) {
                int ct = ch * 2 + ct2;
                int col = colbase + ct * 16 + lm;
                float b = ob1[col];
                #pragma unroll
                for (int mt = 0; mt < 4; ++mt)
                    #pragma unroll
                    for (int g = 0; g < 4; ++g)
                        res[mt][ct][g] = (__bf16)fmaxf(ta[mt][ct2][g] + b, 0.f);
            }
        }
    }
    __syncthreads();   // all x reads complete before overwrite

    // ---- write [h1 | t1] back into s_x ----
    {
        const int colW = (roleB ? 0 : 256) + colbase;
        #pragma unroll
        for (int ct = 0; ct < 4; ++ct) {
            int col = colW + ct * 16 + lm;
            #pragma unroll
            for (int mt = 0; mt < 4; ++mt)
                #pragma unroll
                for (int g = 0; g < 4; ++g)
                    s_x[(mt * 16 + kg * 4 + g) * PITCH_E + col] = res[mt][ct][g];
        }
    }
    __syncthreads();

    // ---- phase 4: h2+control (waves 0-3) | t2+speed (waves 4-7), two row-halves ----
    const __bf16* aHbase = s_x + lm * PITCH_E + (roleB ? 0 : 256) + kg * 8;
    if (roleB) {
        for (int c = cmin; c <= cmax; ++c) {
            const __bf16* bb = PK + PKO_BW2 + (unsigned)c * 65536u + laneoffB;
            #pragma unroll
            for (int rh = 0; rh < 2; ++rh) {
                f32x4 hh[2][4];
                #pragma unroll
                for (int mt = 0; mt < 2; ++mt)
                    #pragma unroll
                    for (int ct = 0; ct < 4; ++ct) hh[mt][ct] = f32x4{0.f, 0.f, 0.f, 0.f};
                #pragma unroll 4
                for (int ks = 0; ks < 8; ++ks) {
                    bf16x8 a0 = *(const bf16x8*)(aHbase + (rh * 2 + 0) * 16 * PITCH_E + ks * 32);
                    bf16x8 a1 = *(const bf16x8*)(aHbase + (rh * 2 + 1) * 16 * PITCH_E + ks * 32);
                    __builtin_amdgcn_s_setprio(1);
                    #pragma unroll
                    for (int ct = 0; ct < 4; ++ct) {
                        bf16x8 bv = *(const bf16x8*)(bb + (size_t)ks * 8192 + ct * 512);
                        hh[0][ct] = __builtin_amdgcn_mfma_f32_16x16x32_bf16(a0, bv, hh[0][ct], 0, 0, 0);
                        hh[1][ct] = __builtin_amdgcn_mfma_f32_16x16x32_bf16(a1, bv, hh[1][ct], 0, 0, 0);
                    }
                    __builtin_amdgcn_s_setprio(0);
                }
                float ph[2][4][3];
                #pragma unroll
                for (int mt = 0; mt < 2; ++mt)
                    #pragma unroll
                    for (int g = 0; g < 4; ++g) { ph[mt][g][0] = 0.f; ph[mt][g][1] = 0.f; ph[mt][g][2] = 0.f; }
                #pragma unroll
                for (int ct = 0; ct < 4; ++ct) {
                    int col = colbase + ct * 16 + lm;
                    float b  = bb2[c * H_ + col];
                    float w0 = bw3[(c * H_ + col) * 3 + 0];
                    float w1 = bw3[(c * H_ + col) * 3 + 1];
                    float w2 = bw3[(c * H_ + col) * 3 + 2];
                    #pragma unroll
                    for (int mt = 0; mt < 2; ++mt)
                        #pragma unroll
                        for (int g = 0; g < 4; ++g) {
                            float h = fmaxf(hh[mt][ct][g] + b, 0.f);
                            ph[mt][g][0] += h * w0; ph[mt][g][1] += h * w1; ph[mt][g][2] += h * w2;
                        }
                }
                #pragma unroll
                for (int mt = 0; mt < 2; ++mt)
                    #pragma unroll
                    for (int g = 0; g < 4; ++g)
                        #pragma unroll
                        for (int o = 0; o < 3; ++o) {
                            float v = ph[mt][g][o];
                            v += __shfl_xor(v, 1); v += __shfl_xor(v, 2);
                            v += __shfl_xor(v, 4); v += __shfl_xor(v, 8);
                            ph[mt][g][o] = v;
                        }
                if (lm == 0) {
                    #pragma unroll
                    for (int mt = 0; mt < 2; ++mt)
                        #pragma unroll
                        for (int g = 0; g < 4; ++g) {
                            int row = (rh * 2 + mt) * 16 + kg * 4 + g;
                            if (s_cmd[row] == c) {
                                atomicAdd(&s_head[row][0], ph[mt][g][0]);
                                atomicAdd(&s_head[row][1], ph[mt][g][1]);
                                atomicAdd(&s_head[row][2], ph[mt][g][2]);
                            }
                        }
                }
            }
        }
    } else {
        float sp[4][4];
        #pragma unroll
        for (int mt = 0; mt < 4; ++mt)
            #pragma unroll
            for (int g = 0; g < 4; ++g) sp[mt][g] = 0.f;
        const __bf16* bb = PK + PKO_OW2 + laneoffB;
        #pragma unroll
        for (int rh = 0; rh < 2; ++rh) {
            f32x4 hh[2][4];
            #pragma unroll
            for (int mt = 0; mt < 2; ++mt)
                #pragma unroll
                for (int ct = 0; ct < 4; ++ct) hh[mt][ct] = f32x4{0.f, 0.f, 0.f, 0.f};
            #pragma unroll 4
            for (int ks = 0; ks < 8; ++ks) {
                bf16x8 a0 = *(const bf16x8*)(aHbase + (rh * 2 + 0) * 16 * PITCH_E + ks * 32);
                bf16x8 a1 = *(const bf16x8*)(aHbase + (rh * 2 + 1) * 16 * PITCH_E + ks * 32);
                __builtin_amdgcn_s_setprio(1);
                #pragma unroll
                for (int ct = 0; ct < 4; ++ct) {
                    bf16x8 bv = *(const bf16x8*)(bb + (size_t)ks * 8192 + ct * 512);
                    hh[0][ct] = __builtin_amdgcn_mfma_f32_16x16x32_bf16(a0, bv, hh[0][ct], 0, 0, 0);
                    hh[1][ct] = __builtin_amdgcn_mfma_f32_16x16x32_bf16(a1, bv, hh[1][ct], 0, 0, 0);
                }
                __builtin_amdgcn_s_setprio(0);
            }
            #pragma unroll
            for (int ct = 0; ct < 4; ++ct) {
                int col = colbase + ct * 16 + lm;
                float b = ob2[col], wv = ow3[col];
                #pragma unroll
                for (int mt = 0; mt < 2; ++mt)
                    #pragma unroll
                    for (int g = 0; g < 4; ++g)
                        sp[rh * 2 + mt][g] += fmaxf(hh[mt][ct][g] + b, 0.f) * wv;
            }
        }
        #pragma unroll
        for (int mt = 0; mt < 4; ++mt)
            #pragma unroll
            for (int g = 0; g < 4; ++g) {
                float v = sp[mt][g];
                v += __shfl_xor(v, 1); v += __shfl_xor(v, 2);
                v += __shfl_xor(v, 4); v += __shfl_xor(v, 8);
                if (lm == 0) atomicAdd(&s_head[mt * 16 + kg * 4 + g][3], v);
            }
    }
    __syncthreads();

    if (tid < 64) {
        int r = s_row[tid], c = s_cmd[tid];
        #pragma unroll
        for (int o = 0; o < 3; ++o) {
            float x = s_head[tid][o] + bb3[c * 3 + o];
            __builtin_nontemporal_store(1.f / (1.f + __expf(-x)), &out[(size_t)r * 3 + o]);
        }
        __builtin_nontemporal_store(s_head[tid][3] + ob3[0], &out[(size_t)3 * B_ + r]);
    }
}

// ---------------- fallback (fp32, no ws) ----------------

__global__ __launch_bounds__(256) void cilrs_slow(
    const float* __restrict__ embedding, const float* __restrict__ speed,
    const int* __restrict__ command,
    const float* __restrict__ sw1, const float* __restrict__ sb1,
    const float* __restrict__ sw2, const float* __restrict__ sb2,
    const float* __restrict__ bw1, const float* __restrict__ bb1,
    const float* __restrict__ bw2, const float* __restrict__ bb2,
    const float* __restrict__ bw3, const float* __restrict__ bb3,
    const float* __restrict__ ow1, const float* __restrict__ ob1,
    const float* __restrict__ ow2, const float* __restrict__ ob2,
    const float* __restrict__ ow3, const float* __restrict__ ob3,
    float* __restrict__ out)
{
    const int row = blockIdx.x;
    const int j   = threadIdx.x;
    __shared__ float sh[H_];
    __shared__ float emb[D_];
    __shared__ float h1[H_];
    __shared__ float h2[H_];
    const float spd = speed[row];
    { float v = spd * sw1[j] + sb1[j]; sh[j] = v > 0.f ? v : 0.f; }
    __syncthreads();
    {
        float a0 = 0.f, a1 = 0.f;
        for (int h = 0; h < H_; ++h) {
            const float s = sh[h];
            a0 += s * sw2[h * D_ + j];
            a1 += s * sw2[h * D_ + j + 256];
        }
        emb[j]       = embedding[(size_t)row * D_ + j]       + a0 + sb2[j];
        emb[j + 256] = embedding[(size_t)row * D_ + j + 256] + a1 + sb2[j + 256];
    }
    __syncthreads();
    const int n = command[row] - 1;
    {
        const float* wp = bw1 + (size_t)n * D_ * H_;
        float a = 0.f;
        for (int d = 0; d < D_; ++d) a += emb[d] * wp[d * H_ + j];
        a += bb1[n * H_ + j];
        h1[j] = a > 0.f ? a : 0.f;
    }
    __syncthreads();
    {
        const float* wp = bw2 + (size_t)n * H_ * H_;
        float a = 0.f;
        for (int h = 0; h < H_; ++h) a += h1[h] * wp[h * H_ + j];
        a += bb2[n * H_ + j];
        h2[j] = a > 0.f ? a : 0.f;
    }
    __syncthreads();
    {
        float a = 0.f;
        for (int d = 0; d < D_; ++d) a += emb[d] * ow1[d * H_ + j];
        a += ob1[j];
        sh[j] = a > 0.f ? a : 0.f;
    }
    __syncthreads();
    {
        float a = 0.f;
        for (int h = 0; h < H_; ++h) a += sh[h] * ow2[h * H_ + j];
        a += ob2[j];
        h1[j] = a > 0.f ? a : 0.f;
    }
    __syncthreads();
    if (j < 3) {
        const float* wp = bw3 + (size_t)n * H_ * 3;
        float a = 0.f;
        for (int h = 0; h < H_; ++h) a += h2[h] * wp[h * 3 + j];
        a += bb3[n * 3 + j];
        out[(size_t)row * 3 + j] = 1.f / (1.f + expf(-a));
    } else if (j == 3) {
        float a = 0.f;
        for (int h = 0; h < H_; ++h) a += h1[h] * ow3[h];
        a += ob3[0];
        out[(size_t)B_ * 3 + row] = a;
    }
}

// ---------------- launch ----------------

extern "C" void kernel_launch(void* const* d_in, const int* in_sizes, int n_in,
                              void* d_out, int out_size, void* d_ws, size_t ws_size,
                              hipStream_t stream) {
    const float* embedding = (const float*)d_in[0];
    const float* speed     = (const float*)d_in[1];
    const int*   command   = (const int*)  d_in[2];
    const float* sw1 = (const float*)d_in[3];
    const float* sb1 = (const float*)d_in[4];
    const float* sw2 = (const float*)d_in[5];
    const float* sb2 = (const float*)d_in[6];
    const float* bw1 = (const float*)d_in[7];
    const float* bb1 = (const float*)d_in[8];
    const float* bw2 = (const float*)d_in[9];
    const float* bb2 = (const float*)d_in[10];
    const float* bw3 = (const float*)d_in[11];
    const float* bb3 = (const float*)d_in[12];
    const float* ow1 = (const float*)d_in[13];
    const float* ob1 = (const float*)d_in[14];
    const float* ow2 = (const float*)d_in[15];
    const float* ob2 = (const float*)d_in[16];
    const float* ow3 = (const float*)d_in[17];
    const float* ob3 = (const float*)d_in[18];
    float* out = (float*)d_out;

    if (ws_size < (size_t)WS_NEEDED) {
        cilrs_slow<<<B_, 256, 0, stream>>>(embedding, speed, command,
                                           sw1, sb1, sw2, sb2,
                                           bw1, bb1, bw2, bb2, bw3, bb3,
                                           ow1, ob1, ow2, ob2, ow3, ob3, out);
        return;
    }

    char* ws = (char*)d_ws;
    int*    counts  = (int*)    ws;          // [0..23]
    int*    cursor2 = (int*)   (ws + 24);    // [24..47]
    int*    perm    = (int*)   (ws + OFF_PERM);
    __bf16* PK      = (__bf16*)(ws + OFF_PACK);

    hipMemsetAsync(ws, 0, 64, stream);
    k_count<<<64, 256, 0, stream>>>(command, counts);
    k_prepB<<<992, 256, 0, stream>>>(command, counts, cursor2, perm,
                                     sw2, bw1, bw2, ow1, ow2, PK);
    k_fused<<<B_ / 64, 512, 0, stream>>>(embedding, speed, command,
                                         sw1, sb1, sb2,
                                         bb1, bb2, bw3, bb3,
                                         ob1, ob2, ow3, ob3,
                                         perm, PK, out);
}